// Round 3
// baseline (94.713 us; speedup 1.0000x reference)
//
#include <hip/hip_runtime.h>
#include <hip/hip_bf16.h>

typedef unsigned int   u32;
typedef unsigned short u16;
typedef unsigned long long u64;

#define NN   8192
#define DD   128
#define CCH  16            // column chunks (grid.x)
#define CHUNK (NN / CCH)   // 512 columns per block
#define JT   64            // j-tile staged in LDS
#define NT   (CHUNK / JT)  // 8 tiles per block
#define GRID (CCH * (NN / 256))   // 512 blocks
#define NFIN 32            // finisher blocks (last 32 arrivals)

#define LOG2E 1.4426950408889634f
#define LN2F  0.6931471805599453f
#define BIAS  32.0f
#define FIXSCALE 4294967296.0   // 2^32 fixed-point for deterministic cross-block sum

typedef __bf16 bf16x8 __attribute__((ext_vector_type(8)));
typedef float  f32x16 __attribute__((ext_vector_type(16)));
typedef float  f32x2  __attribute__((ext_vector_type(2)));

__device__ __forceinline__ u16 f2bf(float x) {
    u32 u = __float_as_uint(x);
    u += 0x7fffu + ((u >> 16) & 1u);   // round-to-nearest-even
    return (u16)(u >> 16);
}

// One wave per row: convert z1,z2 to bf16, compute -sq2*log2e - BIAS and fp32 diagonal.
// Block 0 also zeroes the control words (stream-ordered before score_kernel).
__global__ __launch_bounds__(256) void prep_kernel(
    const float* __restrict__ z1, const float* __restrict__ z2,
    u32* __restrict__ b1, u32* __restrict__ b2,
    float* __restrict__ negsq2b, float* __restrict__ diag, u32* __restrict__ ctrl)
{
    if (blockIdx.x == 0 && threadIdx.x < 4) ctrl[threadIdx.x] = 0;  // counter, counter2, acc64 lo/hi
    int row  = blockIdx.x * 4 + (threadIdx.x >> 6);
    int lane = threadIdx.x & 63;
    float2 a = reinterpret_cast<const float2*>(z1)[row * 64 + lane];
    float2 b = reinterpret_cast<const float2*>(z2)[row * 64 + lane];
    b1[row * 64 + lane] = (u32)f2bf(a.x) | ((u32)f2bf(a.y) << 16);
    b2[row * 64 + lane] = (u32)f2bf(b.x) | ((u32)f2bf(b.y) << 16);
    float dot = a.x * b.x + a.y * b.y;
    float sq  = b.x * b.x + b.y * b.y;
    #pragma unroll
    for (int o = 32; o > 0; o >>= 1) {
        dot += __shfl_xor(dot, o);
        sq  += __shfl_xor(sq, o);
    }
    if (lane == 0) {
        negsq2b[row] = -sq * LOG2E - BIAS;
        diag[row]    = 2.0f * dot - sq;
    }
}

// Main kernel: GEMM + fixed-bias exp-sum + integrated deterministic finalize.
__global__ __launch_bounds__(256, 2) void score_kernel(
    const u16* __restrict__ b1, const u16* __restrict__ b2,
    const float* __restrict__ negsq2b, const float* __restrict__ diag,
    float* __restrict__ partS, u32* __restrict__ ctrl, float* __restrict__ out)
{
    __shared__ alignas(16) u16 tile[3][JT * DD];   // 3 x 16 KB
    __shared__ float nqs[CHUNK];                    // 2 KB: this chunk's negsq2b
    __shared__ u32 rankS;
    __shared__ float red[4];

    const int tid  = threadIdx.x;
    const int lane = tid & 63;
    const int wid  = tid >> 6;
    const int r    = lane & 31, hi = lane >> 5;
    const int chunk = blockIdx.x;
    const int j0    = chunk * CHUNK;
    const int i0w   = blockIdx.y * 256 + wid * 64;

    // z1 fragments (B operand), register-resident: 2 spans x 8 k-slices
    bf16x8 zf0[8], zf1[8];
    #pragma unroll
    for (int kk = 0; kk < 8; ++kk) {
        zf0[kk] = *reinterpret_cast<const bf16x8*>(b1 + (size_t)(i0w + r)      * DD + kk * 16 + hi * 8);
        zf1[kk] = *reinterpret_cast<const bf16x8*>(b1 + (size_t)(i0w + 32 + r) * DD + kk * 16 + hi * 8);
    }
    // stage this chunk's negsq2b into LDS (keeps the main loop free of extra VMEM ops)
    {
        float2 v = reinterpret_cast<const float2*>(negsq2b + j0)[tid];
        *reinterpret_cast<float2*>(&nqs[2 * tid]) = v;
    }
    __syncthreads();   // one-time full drain: zf + nqs staged; vmcnt now 0

    const int sl   = lane & 15;
    const int rrow = lane >> 4;
    auto stage = [&](int t, u16* dst_base) {
        #pragma unroll
        for (int u = 0; u < 4; ++u) {
            int row   = wid * 16 + u * 4 + rrow;
            int gslot = sl ^ (row & 15);                   // inverse-swizzled source (rule #21)
            const u16* src = b2 + (size_t)(j0 + t * JT + row) * DD + gslot * 8;
            __builtin_amdgcn_global_load_lds(
                (const __attribute__((address_space(1))) void*)src,
                (__attribute__((address_space(3))) void*)(dst_base + (wid * 16 + u * 4) * DD),
                16, 0, 0);
        }
    };

    u16 *pa = tile[0], *pb = tile[1], *pc = tile[2];
    stage(0, pa);
    stage(1, pb);

    const f32x2 c2 = {2.0f * LOG2E, 2.0f * LOG2E};
    const int sw = r & 15;
    f32x2 sA0 = {0.f, 0.f}, sA1 = {0.f, 0.f}, sB0 = {0.f, 0.f}, sB1 = {0.f, 0.f};

    for (int t = 0; t < NT; ++t) {
        // counted wait: newest 4 (next tile's stage) may stay in flight; this tile's done
        asm volatile("s_waitcnt vmcnt(4)" ::: "memory");
        __builtin_amdgcn_s_barrier();
        __builtin_amdgcn_sched_barrier(0);
        if (t + 2 < NT) stage(t + 2, pc);
        const u16* tp = pa;
        #pragma unroll
        for (int jj = 0; jj < 2; ++jj) {
            const float* nql = nqs + t * JT + jj * 32 + 4 * hi;
            float4 nq0 = *reinterpret_cast<const float4*>(nql);
            float4 nq1 = *reinterpret_cast<const float4*>(nql + 8);
            float4 nq2 = *reinterpret_cast<const float4*>(nql + 16);
            float4 nq3 = *reinterpret_cast<const float4*>(nql + 24);
            bf16x8 av[8];
            #pragma unroll
            for (int kk = 0; kk < 8; ++kk)
                av[kk] = *reinterpret_cast<const bf16x8*>(tp + (jj * 32 + r) * DD + (((2 * kk + hi) ^ sw) << 3));
            f32x16 acc0 = {0.f}; f32x16 acc1 = {0.f};
            __builtin_amdgcn_s_setprio(1);
            #pragma unroll
            for (int kk = 0; kk < 8; ++kk) {
                acc0 = __builtin_amdgcn_mfma_f32_32x32x16_bf16(av[kk], zf0[kk], acc0, 0, 0, 0);
                acc1 = __builtin_amdgcn_mfma_f32_32x32x16_bf16(av[kk], zf1[kk], acc1, 0, 0, 0);
            }
            __builtin_amdgcn_s_setprio(0);
            const float4 nqm[4] = {nq0, nq1, nq2, nq3};
            #pragma unroll
            for (int m = 0; m < 4; ++m) {
                f32x2 n01 = {nqm[m].x, nqm[m].y}, n23 = {nqm[m].z, nqm[m].w};
                f32x2 a01 = {acc0[4*m], acc0[4*m+1]}, a23 = {acc0[4*m+2], acc0[4*m+3]};
                f32x2 t01 = a01 * c2 + n01, t23 = a23 * c2 + n23;
                f32x2 e01 = {__builtin_amdgcn_exp2f(t01.x), __builtin_amdgcn_exp2f(t01.y)};
                f32x2 e23 = {__builtin_amdgcn_exp2f(t23.x), __builtin_amdgcn_exp2f(t23.y)};
                sA0 += e01; sA1 += e23;
                f32x2 b01 = {acc1[4*m], acc1[4*m+1]}, b23 = {acc1[4*m+2], acc1[4*m+3]};
                f32x2 u01 = b01 * c2 + n01, u23 = b23 * c2 + n23;
                f32x2 f01 = {__builtin_amdgcn_exp2f(u01.x), __builtin_amdgcn_exp2f(u01.y)};
                f32x2 f23 = {__builtin_amdgcn_exp2f(u23.x), __builtin_amdgcn_exp2f(u23.y)};
                sB0 += f01; sB1 += f23;
            }
        }
        u16* tmp = pa; pa = pb; pb = pc; pc = tmp;   // rotate 3 buffers
    }

    float sum0 = (sA0.x + sA0.y) + (sA1.x + sA1.y);
    float sum1 = (sB0.x + sB0.y) + (sB1.x + sB1.y);
    sum0 += __shfl_xor(sum0, 32);
    sum1 += __shfl_xor(sum1, 32);
    if (hi == 0) {
        partS[(size_t)(i0w + r)      * CCH + chunk] = sum0;
        partS[(size_t)(i0w + 32 + r) * CCH + chunk] = sum1;
    }

    // ---- integrated deterministic finalize (last-arrival finishers) ----
    u32* counter  = ctrl;
    u32* counter2 = ctrl + 1;
    u64* acc64    = (u64*)(ctrl + 2);

    __threadfence();               // release partS writes (device scope)
    __syncthreads();
    if (tid == 0) rankS = atomicAdd(counter, 1u);
    __syncthreads();
    const u32 rank = rankS;
    if (rank >= GRID - NFIN) {
        if (tid == 0) {            // wait for ALL blocks' partS (deadlock-free: <=31 blocks pending)
            while (__hip_atomic_load(counter, __ATOMIC_RELAXED, __HIP_MEMORY_SCOPE_AGENT) < GRID)
                __builtin_amdgcn_s_sleep(2);
        }
        __syncthreads();
        __threadfence();           // acquire
        const int slice = (int)rank - (GRID - NFIN);   // 0..31
        const int row   = slice * 256 + tid;
        const float4* pr = reinterpret_cast<const float4*>(partS + (size_t)row * CCH);
        float4 q0 = pr[0], q1 = pr[1], q2 = pr[2], q3 = pr[3];
        float s = ((q0.x + q0.y) + (q0.z + q0.w)) + ((q1.x + q1.y) + (q1.z + q1.w))
                + ((q2.x + q2.y) + (q2.z + q2.w)) + ((q3.x + q3.y) + (q3.z + q3.w));
        float lse = (BIAS + __builtin_amdgcn_logf(s)) * LN2F;   // v_log_f32 = log2
        float a = lse - diag[row];
        #pragma unroll
        for (int o = 32; o > 0; o >>= 1) a += __shfl_xor(a, o);
        if (lane == 0) red[wid] = a;
        __syncthreads();
        if (tid == 0) {
            float tot = (red[0] + red[1]) + (red[2] + red[3]);
            long long v = (long long)llrint((double)tot * FIXSCALE);
            atomicAdd(acc64, (u64)v);          // integer add: order-free, deterministic
            __threadfence();
            u32 o2 = atomicAdd(counter2, 1u);
            if (o2 == NFIN - 1) {
                __threadfence();
                long long total = (long long)__hip_atomic_load(acc64, __ATOMIC_RELAXED, __HIP_MEMORY_SCOPE_AGENT);
                out[0] = (float)((double)total / FIXSCALE / (double)NN);
            }
        }
    }
}

extern "C" void kernel_launch(void* const* d_in, const int* in_sizes, int n_in,
                              void* d_out, int out_size, void* d_ws, size_t ws_size,
                              hipStream_t stream)
{
    const float* z1 = (const float*)d_in[0];
    const float* z2 = (const float*)d_in[1];
    char* ws = (char*)d_ws;

    const size_t bf_bytes = (size_t)NN * DD * 2;   // 2 MB each
    u32*   b1      = (u32*)ws;
    u32*   b2      = (u32*)(ws + bf_bytes);
    float* negsq2b = (float*)(ws + 2 * bf_bytes);
    float* diag    = (float*)(ws + 2 * bf_bytes + (size_t)NN * 4);
    float* partS   = (float*)(ws + 2 * bf_bytes + (size_t)NN * 8);
    u32*   ctrl    = (u32*)(ws + 2 * bf_bytes + (size_t)NN * 8 + (size_t)NN * CCH * 4);
    float* out     = (float*)d_out;

    prep_kernel<<<NN / 4, 256, 0, stream>>>(z1, z2, b1, b2, negsq2b, diag, ctrl);
    score_kernel<<<dim3(CCH, NN / 256), 256, 0, stream>>>(
        (const u16*)b1, (const u16*)b2, negsq2b, diag, partS, ctrl, out);
}

// Round 4
// 85.665 us; speedup vs baseline: 1.1056x; 1.1056x over previous
//
#include <hip/hip_runtime.h>
#include <hip/hip_bf16.h>

typedef unsigned int   u32;
typedef unsigned short u16;

#define NN   8192
#define DD   128
#define CCH  32            // column chunks (grid.x)  -- R3: 16 -> 32 for occupancy
#define CHUNK (NN / CCH)   // 256 columns per block
#define JT   64            // j-tile staged in LDS
#define NT   (CHUNK / JT)  // 4 tiles per block

#define LOG2E 1.4426950408889634f
#define LN2F  0.6931471805599453f
#define BIAS  32.0f

typedef __bf16 bf16x8 __attribute__((ext_vector_type(8)));
typedef float  f32x16 __attribute__((ext_vector_type(16)));
typedef float  f32x2  __attribute__((ext_vector_type(2)));

__device__ __forceinline__ u16 f2bf(float x) {
    u32 u = __float_as_uint(x);
    u += 0x7fffu + ((u >> 16) & 1u);   // round-to-nearest-even
    return (u16)(u >> 16);
}

// One wave per row: convert z1,z2 to bf16, compute -sq2*log2e - BIAS and fp32 diagonal.
__global__ __launch_bounds__(256) void prep_kernel(
    const float* __restrict__ z1, const float* __restrict__ z2,
    u32* __restrict__ b1, u32* __restrict__ b2,
    float* __restrict__ negsq2b, float* __restrict__ diag)
{
    int row  = blockIdx.x * 4 + (threadIdx.x >> 6);
    int lane = threadIdx.x & 63;
    float2 a = reinterpret_cast<const float2*>(z1)[row * 64 + lane];
    float2 b = reinterpret_cast<const float2*>(z2)[row * 64 + lane];
    b1[row * 64 + lane] = (u32)f2bf(a.x) | ((u32)f2bf(a.y) << 16);
    b2[row * 64 + lane] = (u32)f2bf(b.x) | ((u32)f2bf(b.y) << 16);
    float dot = a.x * b.x + a.y * b.y;
    float sq  = b.x * b.x + b.y * b.y;
    #pragma unroll
    for (int o = 32; o > 0; o >>= 1) {
        dot += __shfl_xor(dot, o);
        sq  += __shfl_xor(sq, o);
    }
    if (lane == 0) {
        negsq2b[row] = -sq * LOG2E - BIAS;
        diag[row]    = 2.0f * dot - sq;
    }
}

// Main: 4 waves x 64 i-rows = 256 rows/block, sweeping CHUNK j-columns.
// mfma_f32_32x32x16_bf16, swapped operands: D[j][i] = z2_j . z1_i.
// LDS: linear [64][128] u16 rows, 16B slots XOR-swizzled by (row&15); filled with
// global_load_lds width=16 from a pre-swizzled per-lane GLOBAL source (rule #21).
// Single __syncthreads per tile, double-buffered prefetch (proven R1 structure).
__global__ __launch_bounds__(256, 4) void score_kernel(
    const u16* __restrict__ b1, const u16* __restrict__ b2,
    const float* __restrict__ negsq2b, float* __restrict__ partS)
{
    __shared__ alignas(16) u16 tile[2][JT * DD];   // 2 x 16 KB
    const int tid  = threadIdx.x;
    const int lane = tid & 63;
    const int wid  = tid >> 6;
    const int r    = lane & 31, hi = lane >> 5;
    const int chunk = blockIdx.x;
    const int j0    = chunk * CHUNK;
    const int i0w   = blockIdx.y * 256 + wid * 64;

    // z1 fragments (B operand), register-resident: 2 spans x 8 k-slices
    bf16x8 zf0[8], zf1[8];
    #pragma unroll
    for (int kk = 0; kk < 8; ++kk) {
        zf0[kk] = *reinterpret_cast<const bf16x8*>(b1 + (size_t)(i0w + r)      * DD + kk * 16 + hi * 8);
        zf1[kk] = *reinterpret_cast<const bf16x8*>(b1 + (size_t)(i0w + 32 + r) * DD + kk * 16 + hi * 8);
    }

    const int sl   = lane & 15;    // staging slot
    const int rrow = lane >> 4;    // staging row-within-4

    auto stage = [&](int t, int buf) {
        #pragma unroll
        for (int u = 0; u < 4; ++u) {
            int row   = wid * 16 + u * 4 + rrow;           // local row 0..63
            int gslot = sl ^ (row & 15);                   // inverse-swizzled source
            const u16* src = b2 + (size_t)(j0 + t * JT + row) * DD + gslot * 8;
            u16* dst = &tile[buf][(wid * 16 + u * 4) * DD]; // wave-uniform; +lane*16B implicit
            __builtin_amdgcn_global_load_lds(
                (const __attribute__((address_space(1))) void*)src,
                (__attribute__((address_space(3))) void*)dst, 16, 0, 0);
        }
    };

    float s0 = 0.f, s1 = 0.f, s2 = 0.f, s3 = 0.f;
    const f32x2 C2v = {2.0f * LOG2E, 2.0f * LOG2E};
    const int sw = r & 15;   // read-side swizzle key (row&15 == r&15, jj*32 ≡ 0 mod 16)

    int cur = 0;
    stage(0, 0);
    for (int t = 0; t < NT; ++t) {
        __syncthreads();                   // drains vmcnt(0): buf[cur] ready, buf[cur^1] free
        if (t + 1 < NT) stage(t + 1, cur ^ 1);
        const u16* tp = tile[cur];
        #pragma unroll
        for (int jj = 0; jj < 2; ++jj) {
            const float* nqb = negsq2b + j0 + t * JT + jj * 32 + 4 * hi;
            float4 nq0 = *reinterpret_cast<const float4*>(nqb);
            float4 nq1 = *reinterpret_cast<const float4*>(nqb + 8);
            float4 nq2 = *reinterpret_cast<const float4*>(nqb + 16);
            float4 nq3 = *reinterpret_cast<const float4*>(nqb + 24);
            bf16x8 av[8];
            #pragma unroll
            for (int kk = 0; kk < 8; ++kk) {
                int off = (jj * 32 + r) * DD + (((2 * kk + hi) ^ sw) << 3);
                av[kk] = *reinterpret_cast<const bf16x8*>(tp + off);
            }
            f32x16 acc0 = {0.f}; f32x16 acc1 = {0.f};
            #pragma unroll
            for (int kk = 0; kk < 8; ++kk) {
                acc0 = __builtin_amdgcn_mfma_f32_32x32x16_bf16(av[kk], zf0[kk], acc0, 0, 0, 0);
                acc1 = __builtin_amdgcn_mfma_f32_32x32x16_bf16(av[kk], zf1[kk], acc1, 0, 0, 0);
            }
            const float nqa[16] = {nq0.x, nq0.y, nq0.z, nq0.w,
                                   nq1.x, nq1.y, nq1.z, nq1.w,
                                   nq2.x, nq2.y, nq2.z, nq2.w,
                                   nq3.x, nq3.y, nq3.z, nq3.w};
            #pragma unroll
            for (int q = 0; q < 8; ++q) {
                f32x2 n2 = {nqa[2 * q], nqa[2 * q + 1]};
                f32x2 a0 = {acc0[2 * q], acc0[2 * q + 1]};
                f32x2 t0 = a0 * C2v + n2;
                s0 += __builtin_amdgcn_exp2f(t0.x);
                s1 += __builtin_amdgcn_exp2f(t0.y);
                f32x2 a1 = {acc1[2 * q], acc1[2 * q + 1]};
                f32x2 t1 = a1 * C2v + n2;
                s2 += __builtin_amdgcn_exp2f(t1.x);
                s3 += __builtin_amdgcn_exp2f(t1.y);
            }
        }
        cur ^= 1;
    }

    float sum0 = s0 + s1, sum1 = s2 + s3;
    sum0 += __shfl_xor(sum0, 32);          // combine hi=0/1 j-halves per i
    sum1 += __shfl_xor(sum1, 32);
    if (hi == 0) {
        partS[(size_t)chunk * NN + i0w + r]      = sum0;
        partS[(size_t)chunk * NN + i0w + 32 + r] = sum1;
    }
}

// Combine the 32 column-chunk partials per row, form lse - diag, block-reduce.
__global__ __launch_bounds__(256) void finalize1_kernel(
    const float* __restrict__ partS, const float* __restrict__ diag,
    float* __restrict__ blocksum)
{
    __shared__ float red[4];
    int r = blockIdx.x * 256 + threadIdx.x;
    float s = 0.f;
    #pragma unroll
    for (int c = 0; c < CCH; ++c) s += partS[(size_t)c * NN + r];
    float lse = (BIAS + __builtin_amdgcn_logf(s)) * LN2F;   // v_log_f32 = log2
    float acc = lse - diag[r];
    #pragma unroll
    for (int o = 32; o > 0; o >>= 1) acc += __shfl_xor(acc, o);
    int lane = threadIdx.x & 63, wid = threadIdx.x >> 6;
    if (lane == 0) red[wid] = acc;
    __syncthreads();
    if (threadIdx.x == 0)
        blocksum[blockIdx.x] = red[0] + red[1] + red[2] + red[3];
}

__global__ void finalize2_kernel(const float* __restrict__ blocksum, float* __restrict__ out)
{
    int lane = threadIdx.x;
    float v = (lane < 32) ? blocksum[lane] : 0.f;
    #pragma unroll
    for (int o = 32; o > 0; o >>= 1) v += __shfl_xor(v, o);
    if (lane == 0) out[0] = v * (1.0f / (float)NN);
}

extern "C" void kernel_launch(void* const* d_in, const int* in_sizes, int n_in,
                              void* d_out, int out_size, void* d_ws, size_t ws_size,
                              hipStream_t stream)
{
    const float* z1 = (const float*)d_in[0];
    const float* z2 = (const float*)d_in[1];
    char* ws = (char*)d_ws;

    const size_t bf_bytes = (size_t)NN * DD * 2;   // 2 MB each
    u32*   b1       = (u32*)ws;
    u32*   b2       = (u32*)(ws + bf_bytes);
    float* negsq2b  = (float*)(ws + 2 * bf_bytes);
    float* diag     = (float*)(ws + 2 * bf_bytes + (size_t)NN * 4);
    float* partS    = (float*)(ws + 2 * bf_bytes + (size_t)NN * 8);
    float* blocksum = (float*)(ws + 2 * bf_bytes + (size_t)NN * 8 + (size_t)CCH * NN * 4);
    float* out      = (float*)d_out;

    prep_kernel<<<NN / 4, 256, 0, stream>>>(z1, z2, b1, b2, negsq2b, diag);
    score_kernel<<<dim3(CCH, NN / 256), 256, 0, stream>>>((const u16*)b1, (const u16*)b2, negsq2b, partS);
    finalize1_kernel<<<NN / 256, 256, 0, stream>>>(partS, diag, blocksum);
    finalize2_kernel<<<1, 64, 0, stream>>>(blocksum, out);
}